// Round 2
// baseline (255.433 us; speedup 1.0000x reference)
//
#include <hip/hip_runtime.h>

// CubicHermite2d: B=32, N=1024, axes are arange(N) => uniform knots, dx=1.
//
// out[b,k,p] = Hx(h0y*row_{Iy} + h2y*row_{Iy+1})(xs[p])
//            + h1y*(S[b,Iy+1,p]-S[b,Iy,p]) + h3y*(S[b,Iy+2,p]-S[b,Iy+1,p])
//
// R1: Hermite_x is linear in the row => stage ONE combined row in LDS
//     (3 random gathers/output). Column terms stay in registers.
// R2:
//   - One block handles 1 y-query x 4 batches: y-weights, xs load, x-weights
//     and the barrier are amortized 4x; 12 float4 loads in flight.
//   - XCD-pinned batches: blockIdx round-robins XCDs with period 8, so
//     xcd = id&7 owns batches 4*xcd..4*xcd+3 -> per-XCD L2 keeps the
//     batch slice; L3 keeps signal resident for the 3x row re-reads.
//   - Non-temporal stores for out: the 128 MiB output stream no longer
//     evicts signal (128 MiB) from the 256 MiB L3 -> HBM fetch ~= compulsory.
// R3: fix — __builtin_nontemporal_store needs a native clang vector type,
//     not HIP_vector_type<float,4>; cast through ext_vector_type(4).

#define NGRID 1024
#define BATCH 32
#define KB    4      // batches per block (BATCH = 8 XCDs * KB)

typedef float nfloat4 __attribute__((ext_vector_type(4)));

__global__ __launch_bounds__(256) void hermite2d_fused(
    const float* __restrict__ signal,   // [B, N, N]
    const float* __restrict__ xs,       // [N]
    const float* __restrict__ ys,       // [N]
    float* __restrict__ out)            // [B, N(k), N(p)]
{
    const unsigned f = blockIdx.x;      // 0..8191
    const int xcd = (int)(f & 7u);      // XCD-pinned batch group
    const int k   = (int)(f >> 3);      // y-query index 0..1023
    const int b0  = xcd * KB;
    const int t   = threadIdx.x;        // 256 threads; each owns columns 4t..4t+3

    __shared__ float crow[KB][NGRID];   // per-batch combined row h0y*r0 + h2y*r1

    // --- y-direction coefficients (block-uniform, computed ONCE for 4 rows) ---
    const float qy = ys[k];
    int Iy = (int)floorf(qy);
    if (Iy < 0) Iy = 0;
    if (Iy > NGRID - 3) Iy = NGRID - 3;
    const float ty  = qy - (float)Iy;
    const float ty2 = ty * ty;
    const float ty3 = ty2 * ty;
    const float h0y = 1.0f - 3.0f * ty2 + 2.0f * ty3;
    const float h1y = ty - 2.0f * ty2 + ty3;
    const float h2y = 3.0f * ty2 - 2.0f * ty3;
    const float h3y = ty3 - ty2;

    // --- stage: 3 rows x 4 batches (float4/thread each), build combined rows ---
    float colp[KB][4];
    #pragma unroll
    for (int i = 0; i < KB; ++i) {
        const float4* src4 =
            (const float4*)(signal + ((size_t)(b0 + i) * NGRID + (size_t)Iy) * NGRID);
        const float4 r0 = src4[t];
        const float4 r1 = src4[t + NGRID / 4];
        const float4 r2 = src4[t + NGRID / 2];

        float4 c;
        c.x = h0y * r0.x + h2y * r1.x;
        c.y = h0y * r0.y + h2y * r1.y;
        c.z = h0y * r0.z + h2y * r1.z;
        c.w = h0y * r0.w + h2y * r1.w;
        ((float4*)crow[i])[t] = c;

        colp[i][0] = h1y * (r1.x - r0.x) + h3y * (r2.x - r1.x);
        colp[i][1] = h1y * (r1.y - r0.y) + h3y * (r2.y - r1.y);
        colp[i][2] = h1y * (r1.z - r0.z) + h3y * (r2.z - r1.z);
        colp[i][3] = h1y * (r1.w - r0.w) + h3y * (r2.w - r1.w);
    }

    const float4 q4 = ((const float4*)xs)[t];
    const float qx[4] = { q4.x, q4.y, q4.z, q4.w };

    __syncthreads();

    // --- x-interp: weights computed once per element, reused for 4 batches ---
    float4 res[KB];
    #pragma unroll
    for (int j = 0; j < 4; ++j) {
        const float q = qx[j];
        int Ix = (int)floorf(q);
        if (Ix < 0) Ix = 0;
        if (Ix > NGRID - 3) Ix = NGRID - 3;
        const float tx = q - (float)Ix;
        const float t2 = tx * tx;
        const float t3 = t2 * tx;
        const float w0 = 1.0f - tx - t2 + t3;
        const float w1 = tx + 2.0f * (t2 - t3);
        const float w2 = t3 - t2;
        #pragma unroll
        for (int i = 0; i < KB; ++i) {
            const float c0 = crow[i][Ix];
            const float c1 = crow[i][Ix + 1];
            const float c2 = crow[i][Ix + 2];
            ((float*)&res[i])[j] = w0 * c0 + w1 * c1 + w2 * c2 + colp[i][j];
        }
    }

    // --- non-temporal stores: don't let out evict signal from L2/L3 ---
    #pragma unroll
    for (int i = 0; i < KB; ++i) {
        nfloat4* orow4 = (nfloat4*)(out + ((size_t)(b0 + i) * NGRID + (size_t)k) * NGRID);
        __builtin_nontemporal_store(*(const nfloat4*)&res[i], &orow4[t]);
    }
}

extern "C" void kernel_launch(void* const* d_in, const int* in_sizes, int n_in,
                              void* d_out, int out_size, void* d_ws, size_t ws_size,
                              hipStream_t stream) {
    // inputs: 0=xaxis[N], 1=yaxis[N], 2=signal[B,N,N], 3=xs[N], 4=ys[N] (all f32)
    const float* signal = (const float*)d_in[2];
    const float* xs     = (const float*)d_in[3];
    const float* ys     = (const float*)d_in[4];
    float* out          = (float*)d_out;

    dim3 grid(NGRID * (BATCH / KB));    // 8192 blocks, 1D: (f&7)=XCD, (f>>3)=k
    hermite2d_fused<<<grid, 256, 0, stream>>>(signal, xs, ys, out);
}

// Round 3
// 253.997 us; speedup vs baseline: 1.0057x; 1.0057x over previous
//
#include <hip/hip_runtime.h>

// CubicHermite2d: B=32, N=1024, axes are arange(N) => uniform knots, dx=1.
//
// out[b,k,p] = Hx(h0y*row_{Iy} + h2y*row_{Iy+1})(xs[p])
//            + h1y*(S[b,Iy+1,p]-S[b,Iy,p]) + h3y*(S[b,Iy+2,p]-S[b,Iy+1,p])
//
// R1: Hermite_x is linear in the row => stage ONE combined row in LDS
//     (3 random gathers/output). Column terms stay in registers.
// R2: 4 batches/block (XCD-pinned), nt-stores  -> FETCH ~= compulsory. BUT
//     kernel went 80->88us: warm-pass (zero fetch) still 88us => LDS-bound,
//     48 ds_read_b32 gathers/thread + 7.4M bank-conflict cycles.
// R4 (this round): BATCH-INTERLEAVED LDS layout.
//     crow[slot][4] : one float4 slot = combined-row value for 4 batches at
//     one column. Gather = 3 ds_read_b128 per output column (12/thread, was
//     48 b32). b128 random gather: 64 lanes over 8 bank-groups ~= structural
//     minimum. Staging writes (stride-16B columns) would be 32-way write
//     conflicts => bijective XOR swizzle slot = c ^ ((c>>3)&7): write groups
//     = e ^ 4(t&1) ^ ((t>>1)&7) cover all 8 groups uniformly.

#define NGRID 1024
#define BATCH 32
#define KB    4      // batches per block (BATCH = 8 XCDs * KB)

typedef float nfloat4 __attribute__((ext_vector_type(4)));

__device__ __forceinline__ int swz(int c) { return c ^ ((c >> 3) & 7); }

__global__ __launch_bounds__(256) void hermite2d_fused(
    const float* __restrict__ signal,   // [B, N, N]
    const float* __restrict__ xs,       // [N]
    const float* __restrict__ ys,       // [N]
    float* __restrict__ out)            // [B, N(k), N(p)]
{
    const unsigned f = blockIdx.x;      // 0..8191
    const int xcd = (int)(f & 7u);      // XCD-pinned batch group
    const int k   = (int)(f >> 3);      // y-query index 0..1023
    const int b0  = xcd * KB;
    const int t   = threadIdx.x;        // 256 threads; each owns columns 4t..4t+3

    // crow[slot] = float4 {batch0..3} of combined row at column c, slot=swz(c)
    __shared__ float4 crow[NGRID];      // 16 KB

    // --- y-direction coefficients (block-uniform) ---
    const float qy = ys[k];
    int Iy = (int)floorf(qy);
    if (Iy < 0) Iy = 0;
    if (Iy > NGRID - 3) Iy = NGRID - 3;
    const float ty  = qy - (float)Iy;
    const float ty2 = ty * ty;
    const float ty3 = ty2 * ty;
    const float h0y = 1.0f - 3.0f * ty2 + 2.0f * ty3;
    const float h1y = ty - 2.0f * ty2 + ty3;
    const float h2y = 3.0f * ty2 - 2.0f * ty3;
    const float h3y = ty3 - ty2;

    const float4 q4 = ((const float4*)xs)[t];
    const float qx[4] = { q4.x, q4.y, q4.z, q4.w };

    // --- stage: 3 rows x 4 batches; combined row cc[i] + column part colp ---
    float4 cc[KB];
    float colp[KB][4];
    #pragma unroll
    for (int i = 0; i < KB; ++i) {
        const float4* src4 =
            (const float4*)(signal + ((size_t)(b0 + i) * NGRID + (size_t)Iy) * NGRID);
        const float4 r0 = src4[t];
        const float4 r1 = src4[t + NGRID / 4];
        const float4 r2 = src4[t + NGRID / 2];

        cc[i].x = h0y * r0.x + h2y * r1.x;
        cc[i].y = h0y * r0.y + h2y * r1.y;
        cc[i].z = h0y * r0.z + h2y * r1.z;
        cc[i].w = h0y * r0.w + h2y * r1.w;

        colp[i][0] = h1y * (r1.x - r0.x) + h3y * (r2.x - r1.x);
        colp[i][1] = h1y * (r1.y - r0.y) + h3y * (r2.y - r1.y);
        colp[i][2] = h1y * (r1.z - r0.z) + h3y * (r2.z - r1.z);
        colp[i][3] = h1y * (r1.w - r0.w) + h3y * (r2.w - r1.w);
    }

    // --- transpose 4x4 in registers, swizzled batch-interleaved LDS write ---
    const float* ccf = (const float*)cc;   // [i*4 + e], all-static indexing
    #pragma unroll
    for (int e = 0; e < 4; ++e) {
        float4 v;
        v.x = ccf[0 * 4 + e];
        v.y = ccf[1 * 4 + e];
        v.z = ccf[2 * 4 + e];
        v.w = ccf[3 * 4 + e];
        crow[swz(4 * t + e)] = v;          // ds_write_b128, conflict-free groups
    }

    __syncthreads();

    // --- x-interp: per output column, 3 ds_read_b128 fetch all 4 batches ---
    float4 res[KB];                        // res[i] = 4 columns (j) of batch i
    #pragma unroll
    for (int j = 0; j < 4; ++j) {
        const float q = qx[j];
        int Ix = (int)floorf(q);
        if (Ix < 0) Ix = 0;
        if (Ix > NGRID - 3) Ix = NGRID - 3;
        const float tx = q - (float)Ix;
        const float t2 = tx * tx;
        const float t3 = t2 * tx;
        const float w0 = 1.0f - tx - t2 + t3;
        const float w1 = tx + 2.0f * (t2 - t3);
        const float w2 = t3 - t2;

        const float4 g0 = crow[swz(Ix)];
        const float4 g1 = crow[swz(Ix + 1)];
        const float4 g2 = crow[swz(Ix + 2)];

        ((float*)&res[0])[j] = w0 * g0.x + w1 * g1.x + w2 * g2.x + colp[0][j];
        ((float*)&res[1])[j] = w0 * g0.y + w1 * g1.y + w2 * g2.y + colp[1][j];
        ((float*)&res[2])[j] = w0 * g0.z + w1 * g1.z + w2 * g2.z + colp[2][j];
        ((float*)&res[3])[j] = w0 * g0.w + w1 * g1.w + w2 * g2.w + colp[3][j];
    }

    // --- non-temporal stores: don't let out evict signal from L2/L3 ---
    #pragma unroll
    for (int i = 0; i < KB; ++i) {
        nfloat4* orow4 = (nfloat4*)(out + ((size_t)(b0 + i) * NGRID + (size_t)k) * NGRID);
        __builtin_nontemporal_store(*(const nfloat4*)&res[i], &orow4[t]);
    }
}

extern "C" void kernel_launch(void* const* d_in, const int* in_sizes, int n_in,
                              void* d_out, int out_size, void* d_ws, size_t ws_size,
                              hipStream_t stream) {
    // inputs: 0=xaxis[N], 1=yaxis[N], 2=signal[B,N,N], 3=xs[N], 4=ys[N] (all f32)
    const float* signal = (const float*)d_in[2];
    const float* xs     = (const float*)d_in[3];
    const float* ys     = (const float*)d_in[4];
    float* out          = (float*)d_out;

    dim3 grid(NGRID * (BATCH / KB));    // 8192 blocks, 1D: (f&7)=XCD, (f>>3)=k
    hermite2d_fused<<<grid, 256, 0, stream>>>(signal, xs, ys, out);
}